// Round 1
// baseline (682.239 us; speedup 1.0000x reference)
//
#include <hip/hip_runtime.h>
#include <hip/hip_bf16.h>
#include <cstdint>

// Problem constants: B=64, T=512, E=256, H=128, 4H=512.
#define BB 64
#define TT 512
#define EE 256
#define HH 128
#define G4 512

typedef _Float16 half2_t __attribute__((ext_vector_type(2)));
typedef _Float16 f16x4 __attribute__((ext_vector_type(4)));
typedef _Float16 f16x8 __attribute__((ext_vector_type(8)));
typedef float f32x4 __attribute__((ext_vector_type(4)));

__device__ __forceinline__ float fdot2f(half2_t a, half2_t b, float c) {
#if defined(__has_builtin)
#if __has_builtin(__builtin_amdgcn_fdot2)
  return __builtin_amdgcn_fdot2(a, b, c, false);
#else
  return c + (float)a[0] * (float)b[0] + (float)a[1] * (float)b[1];
#endif
#else
  return c + (float)a[0] * (float)b[0] + (float)a[1] * (float)b[1];
#endif
}

__device__ __forceinline__ float rcp_(float x) { return __builtin_amdgcn_rcpf(x); }
__device__ __forceinline__ float sigmoid_(float x) {
  return rcp_(1.f + __expf(-x));
}
__device__ __forceinline__ float tanh_(float x) {
  float ax = fabsf(x);
  float e = __expf(-2.f * ax);             // in (0,1], no overflow ever
  float r = (1.f - e) * rcp_(1.f + e);
  return copysignf(r, x);
}

// ---------------------------------------------------------------------------
// Kernel A: trans = row-softmax(transition); W16 = (f16)W_ih
// grid 256 x 128 threads. blocks 0..127: softmax row; 128..255: W_ih convert.
// ---------------------------------------------------------------------------
__global__ __launch_bounds__(128) void prep_kernel(
    const float* __restrict__ transition, const float* __restrict__ W_ih,
    float* __restrict__ trans, _Float16* __restrict__ W16) {
  const int bid = blockIdx.x, t = threadIdx.x;
  if (bid < 128) {
    __shared__ float red[2];
    float v = transition[bid * HH + t];
    float m = v;
#pragma unroll
    for (int s = 32; s >= 1; s >>= 1) m = fmaxf(m, __shfl_xor(m, s));
    if ((t & 63) == 0) red[t >> 6] = m;
    __syncthreads();
    m = fmaxf(red[0], red[1]);
    float e = __expf(v - m);
    float s = e;
#pragma unroll
    for (int k = 32; k >= 1; k >>= 1) s += __shfl_xor(s, k);
    __syncthreads();  // protect red before reuse
    if ((t & 63) == 0) red[t >> 6] = s;
    __syncthreads();
    trans[bid * HH + t] = e * rcp_(red[0] + red[1]);
  } else {
    const int base = (bid - 128) * 1024 + t * 8;  // 131072 total elems
    float4 v0 = *(const float4*)(W_ih + base);
    float4 v1 = *(const float4*)(W_ih + base + 4);
    f16x8 h;
    h[0] = (_Float16)v0.x; h[1] = (_Float16)v0.y;
    h[2] = (_Float16)v0.z; h[3] = (_Float16)v0.w;
    h[4] = (_Float16)v1.x; h[5] = (_Float16)v1.y;
    h[6] = (_Float16)v1.z; h[7] = (_Float16)v1.w;
    *(f16x8*)(W16 + base) = h;
  }
}

// ---------------------------------------------------------------------------
// Kernel B: precomp[m][j] = sum_e inputs[m][e]*W_ih[j][e] + b_ih[j] + b_hh[j]
// M=32768, N=512, K=256.  MFMA f16 16x16x32.  BM=64 (LDS-staged), BN=256
// (4 waves x 64 cols, B-frags straight from L2-resident W16).
// grid (512, 2) x 256 threads.
// ---------------------------------------------------------------------------
__global__ __launch_bounds__(256) void gemm_in(
    const float* __restrict__ A, const _Float16* __restrict__ W16,
    const float* __restrict__ b_ih, const float* __restrict__ b_hh,
    float* __restrict__ out) {
  __shared__ _Float16 As[64][264];  // K=256 + 8 pad (16B-aligned rows)
  const int t = threadIdx.x;
  const int m0 = blockIdx.x * 64;
  const int n0 = blockIdx.y * 256;
  {
    const int c4 = t & 63, r0 = t >> 6;
#pragma unroll
    for (int p = 0; p < 16; ++p) {
      const int row = r0 + 4 * p;
      float4 v = *(const float4*)(A + (size_t)(m0 + row) * EE + c4 * 4);
      f16x4 h;
      h[0] = (_Float16)v.x; h[1] = (_Float16)v.y;
      h[2] = (_Float16)v.z; h[3] = (_Float16)v.w;
      *(f16x4*)&As[row][c4 * 4] = h;
    }
  }
  __syncthreads();
  const int w = t >> 6, L = t & 63;
  const int lrow = L & 15, quad = L >> 4, lk = quad * 8;
  f32x4 acc[4][4] = {};
  const _Float16* Wbase = W16 + (size_t)(n0 + w * 64) * EE;
#pragma unroll
  for (int kc = 0; kc < 8; ++kc) {
    f16x8 a[4], bf[4];
#pragma unroll
    for (int mf = 0; mf < 4; ++mf)
      a[mf] = *(const f16x8*)&As[mf * 16 + lrow][kc * 32 + lk];
#pragma unroll
    for (int nf = 0; nf < 4; ++nf)
      bf[nf] = *(const f16x8*)(Wbase + (size_t)(nf * 16 + lrow) * EE + kc * 32 + lk);
#pragma unroll
    for (int mf = 0; mf < 4; ++mf)
#pragma unroll
      for (int nf = 0; nf < 4; ++nf)
        acc[mf][nf] = __builtin_amdgcn_mfma_f32_16x16x32_f16(a[mf], bf[nf], acc[mf][nf], 0, 0, 0);
  }
#pragma unroll
  for (int nf = 0; nf < 4; ++nf) {
    const int j = n0 + w * 64 + nf * 16 + lrow;  // C/D: col = lane&15
    const float bias = b_ih[j] + b_hh[j];
#pragma unroll
    for (int mf = 0; mf < 4; ++mf) {
#pragma unroll
      for (int r = 0; r < 4; ++r) {  // C/D: row = quad*4 + r
        const int m = m0 + mf * 16 + quad * 4 + r;
        out[(size_t)m * G4 + j] = acc[mf][nf][r] + bias;
      }
    }
  }
}

// ---------------------------------------------------------------------------
// Kernel C: fused LSTM recurrence + per-step softmax + CRF forward + emit.
// One workgroup (512 thr = 8 waves) per batch.  W_hh rows in f16 regs
// (thread t owns gate row t), h broadcast via LDS.  CRF LSE as matvec with
// exp(trans) columns in f16 regs (thread: j = t&127, k-quarter q = t>>7).
// out_b[b] = Ps - emit  (transition gold score handled in finalize).
// ---------------------------------------------------------------------------
__global__ __launch_bounds__(512, 2) void lstm_crf(
    const float* __restrict__ precomp, const float* __restrict__ Whh,
    const float* __restrict__ trans, const int* __restrict__ labels,
    float* __restrict__ out_b) {
  const int b = blockIdx.x, t = threadIdx.x;
  __shared__ __align__(16) _Float16 h_lds[HH];
  __shared__ __align__(16) _Float16 E_lds[HH];
  __shared__ float act[G4];
  __shared__ float Spart[4][132];
  __shared__ float p_lds[HH];
  __shared__ float red[2];
  __shared__ float pre0[2];
  __shared__ float fin[4];
  __shared__ int lab[TT];

  // --- one-time loads -------------------------------------------------------
  half2_t w[64];  // W_hh[t][0..127] as f16 pairs
  {
    const float4* wr = (const float4*)(Whh + (size_t)t * HH);
#pragma unroll
    for (int i = 0; i < 32; ++i) {
      float4 v = wr[i];
      half2_t a, c2;
      a[0] = (_Float16)v.x; a[1] = (_Float16)v.y;
      c2[0] = (_Float16)v.z; c2[1] = (_Float16)v.w;
      w[2 * i] = a; w[2 * i + 1] = c2;
    }
  }
  const int q = t >> 7, j = t & 127;
  half2_t et[16];  // exp(trans[q*32 + 2a (+1)][j])
#pragma unroll
  for (int a2 = 0; a2 < 16; ++a2) {
    float e0 = __expf(trans[(q * 32 + 2 * a2) * HH + j]);
    float e1 = __expf(trans[(q * 32 + 2 * a2 + 1) * HH + j]);
    half2_t hh; hh[0] = (_Float16)e0; hh[1] = (_Float16)e1;
    et[a2] = hh;
  }
  lab[t] = labels[b * TT + t];
  float tr0 = 0.f, tr127 = 0.f;
  if (t < HH) {
    h_lds[t] = (_Float16)0.f;
    E_lds[t] = (_Float16)0.f;
    tr0 = trans[t];
    tr127 = trans[127 * HH + t];
  }
  float c = 0.f, pre = 0.f, mused = 0.f, emit = 0.f;
  const float* pc = precomp + (size_t)b * TT * G4 + t;
  float nxt = pc[0];
  __syncthreads();

#pragma unroll 1
  for (int step = 0; step < TT; ++step) {
    const float cur = nxt;
    if (step < TT - 1) nxt = pc[(size_t)(step + 1) * G4];
    // --- phase 1: LSTM matvec (h from prev step) + CRF matvec (E prev) -----
    float a0 = 0.f, a1 = 0.f;
#pragma unroll
    for (int ch = 0; ch < 8; ++ch) {
      float4 hb = *((const float4*)h_lds + ch);  // 8 halves, broadcast read
      half2_t h0 = __builtin_bit_cast(half2_t, hb.x);
      half2_t h1 = __builtin_bit_cast(half2_t, hb.y);
      half2_t h2 = __builtin_bit_cast(half2_t, hb.z);
      half2_t h3 = __builtin_bit_cast(half2_t, hb.w);
      a0 = fdot2f(w[4 * ch + 0], h0, a0);
      a1 = fdot2f(w[4 * ch + 1], h1, a1);
      a0 = fdot2f(w[4 * ch + 2], h2, a0);
      a1 = fdot2f(w[4 * ch + 3], h3, a1);
    }
    const float gate = cur + a0 + a1;
    float s0 = 0.f;
#pragma unroll
    for (int ec = 0; ec < 4; ++ec) {
      float4 eb = *((const float4*)E_lds + q * 4 + ec);
      half2_t e0 = __builtin_bit_cast(half2_t, eb.x);
      half2_t e1 = __builtin_bit_cast(half2_t, eb.y);
      half2_t e2 = __builtin_bit_cast(half2_t, eb.z);
      half2_t e3 = __builtin_bit_cast(half2_t, eb.w);
      s0 = fdot2f(et[4 * ec + 0], e0, s0);
      s0 = fdot2f(et[4 * ec + 1], e1, s0);
      s0 = fdot2f(et[4 * ec + 2], e2, s0);
      s0 = fdot2f(et[4 * ec + 3], e3, s0);
    }
    if (t == 256 && step > 0) emit += p_lds[lab[step - 1]];  // prev step's p
    const float av = ((t >> 7) == 2) ? tanh_(gate) : sigmoid_(gate);
    act[t] = av;
    Spart[q][j] = s0;
    __syncthreads();  // A
    // --- phase 3 (threads 0..127): cell update, softmax, CRF update --------
    float e = 0.f, hval = 0.f;
    if (t < HH) {
      const float iv = act[t], fv = act[t + 128], gv = act[t + 256], ov = act[t + 384];
      c = fv * c + iv * gv;
      hval = ov * tanh_(c);
      e = __expf(hval);  // |hval|<1, no max-sub needed
      float s = e;
#pragma unroll
      for (int m = 32; m >= 1; m >>= 1) s += __shfl_xor(s, m);
      if ((t & 63) == 0) red[t >> 6] = s;
    }
    __syncthreads();  // B
    if (t < HH) {
      const float tot = red[0] + red[1];
      const float pj = e * rcp_(tot);
      const float S = Spart[0][t] + Spart[1][t] + Spart[2][t] + Spart[3][t];
      if (step == 0)
        pre = pj + tr0;
      else
        pre = pj + mused + __logf(S);
      if (t == 0) pre0[step & 1] = pre;
      const float M = (step == 0) ? 0.f : pre0[(step + 1) & 1];  // pre_0(step-1)
      mused = M;
      E_lds[t] = (_Float16)__expf(pre - M);  // bounded in [~0.8, ~9.5] -> f16 safe
      h_lds[t] = (_Float16)hval;
      p_lds[t] = pj;
    }
    __syncthreads();  // D
  }
  // --- epilogue: Ps = LSE(pre + trans[127]); out_b = Ps - emit --------------
  if (t == 256) fin[0] = emit + p_lds[lab[TT - 1]];
  float v = 0.f;
  if (t < HH) {
    v = pre + tr127;
    float m = v;
#pragma unroll
    for (int s2 = 32; s2 >= 1; s2 >>= 1) m = fmaxf(m, __shfl_xor(m, s2));
    if ((t & 63) == 0) fin[1 + (t >> 6)] = m;
  }
  __syncthreads();
  if (t < HH) {
    const float M2 = fmaxf(fin[1], fin[2]);
    float ex = __expf(v - M2);
#pragma unroll
    for (int s2 = 32; s2 >= 1; s2 >>= 1) ex += __shfl_xor(ex, s2);
    if ((t & 63) == 0) red[t >> 6] = ex;
  }
  __syncthreads();
  if (t == 0) {
    const float Ps = fmaxf(fin[1], fin[2]) + __logf(red[0] + red[1]);
    out_b[b] = Ps - fin[0];
  }
}

// ---------------------------------------------------------------------------
// Kernel D: total = sum_b out_b[b] - sum_{b,t<511} trans[l_t][l_{t+1}]
// ---------------------------------------------------------------------------
__global__ __launch_bounds__(512) void finalize_kernel(
    const float* __restrict__ trans, const int* __restrict__ labels,
    const float* __restrict__ out_b, float* __restrict__ d_out) {
  const int t = threadIdx.x;
  float a = 0.f;
  if (t < TT - 1) {
    for (int b = 0; b < BB; ++b) {
      const int l0 = labels[b * TT + t];
      const int l1 = labels[b * TT + t + 1];
      a += trans[l0 * HH + l1];
    }
  }
  float x = ((t < BB) ? out_b[t] : 0.f) - a;
  __shared__ float red[8];
#pragma unroll
  for (int s = 32; s >= 1; s >>= 1) x += __shfl_xor(x, s);
  if ((t & 63) == 0) red[t >> 6] = x;
  __syncthreads();
  if (t == 0) {
    float s = 0.f;
#pragma unroll
    for (int i = 0; i < 8; ++i) s += red[i];
    d_out[0] = s;
  }
}

// ---------------------------------------------------------------------------
extern "C" void kernel_launch(void* const* d_in, const int* in_sizes, int n_in,
                              void* d_out, int out_size, void* d_ws, size_t ws_size,
                              hipStream_t stream) {
  const float* inputs = (const float*)d_in[0];      // (64,512,256) f32
  const int* labels = (const int*)d_in[1];          // (64,512) i32
  const float* W_ih = (const float*)d_in[2];        // (512,256) f32
  const float* W_hh = (const float*)d_in[3];        // (512,128) f32
  const float* b_ih = (const float*)d_in[4];        // (512,) f32
  const float* b_hh = (const float*)d_in[5];        // (512,) f32
  const float* transition = (const float*)d_in[6];  // (128,128) f32

  char* ws = (char*)d_ws;
  float* precomp = (float*)ws;                           // 64 MiB
  float* trans = (float*)(ws + 67108864);                // 64 KiB
  _Float16* W16 = (_Float16*)(ws + 67108864 + 65536);    // 256 KiB
  float* out_b = (float*)(ws + 67108864 + 65536 + 262144);

  prep_kernel<<<256, 128, 0, stream>>>(transition, W_ih, trans, W16);
  gemm_in<<<dim3(512, 2), 256, 0, stream>>>(inputs, W16, b_ih, b_hh, precomp);
  lstm_crf<<<64, 512, 0, stream>>>(precomp, W_hh, trans, labels, out_b);
  finalize_kernel<<<1, 512, 0, stream>>>(trans, labels, out_b, (float*)d_out);
}